// Round 3
// baseline (8395.652 us; speedup 1.0000x reference)
//
#include <hip/hip_runtime.h>

#define E_CNT 80000
#define N_NODES 10000

__device__ __forceinline__ float sigmoidf_(float x) { return 1.f / (1.f + __expf(-x)); }

__device__ __forceinline__ unsigned fkey(float f) {
  unsigned u = __float_as_uint(f);
  return (u & 0x80000000u) ? ~u : (u | 0x80000000u);
}
__device__ __forceinline__ float unfkey(unsigned k) {
  unsigned u = (k & 0x80000000u) ? (k & 0x7FFFFFFFu) : ~k;
  return __uint_as_float(u);
}

// ---------------------------------------------------------------------------
// Phase 1.  16 edges/block, 256 threads. Single-column stage-5 GEMM with
// depth-8 register prefetch of w0 (spill-safe: every acc-indexing loop is
// explicitly unrolled — rule #20).
// ---------------------------------------------------------------------------

__device__ __forceinline__ void k1_gemm(const float* x0t, const float* __restrict__ wp,
                                        float acc[16]) {
  const float4* x4 = (const float4*)x0t;
  float wA[8], nA[8];
#pragma unroll
  for (int i = 0; i < 16; ++i) acc[i] = 0.f;
#pragma unroll
  for (int i = 0; i < 8; ++i) wA[i] = wp[(size_t)i * 768];
  for (int kb = 0; kb < 384; kb += 8) {
    if (kb < 376) {
#pragma unroll
      for (int i = 0; i < 8; ++i) nA[i] = wp[(size_t)(kb + 8 + i) * 768];
    }
#pragma unroll
    for (int u = 0; u < 8; ++u) {
      const int k = kb + u;
      float4 a0 = x4[k * 4 + 0];
      float4 a1 = x4[k * 4 + 1];
      float4 a2 = x4[k * 4 + 2];
      float4 a3 = x4[k * 4 + 3];
      float wa = wA[u];
      acc[0]  += a0.x * wa; acc[1]  += a0.y * wa; acc[2]  += a0.z * wa; acc[3]  += a0.w * wa;
      acc[4]  += a1.x * wa; acc[5]  += a1.y * wa; acc[6]  += a1.z * wa; acc[7]  += a1.w * wa;
      acc[8]  += a2.x * wa; acc[9]  += a2.y * wa; acc[10] += a2.z * wa; acc[11] += a2.w * wa;
      acc[12] += a3.x * wa; acc[13] += a3.y * wa; acc[14] += a3.z * wa; acc[15] += a3.w * wa;
    }
#pragma unroll
    for (int i = 0; i < 8; ++i) wA[i] = nA[i];
  }
}

__global__ __launch_bounds__(256, 2) void k_phase1(
    const float* __restrict__ x, const int* __restrict__ an,
    const float* __restrict__ edist, const int* __restrict__ eidx,
    const float* __restrict__ wigner,
    const float* __restrict__ semb, const float* __restrict__ temb,
    const float* __restrict__ rw1, const float* __restrict__ rb1,
    const float* __restrict__ rlnw, const float* __restrict__ rlnb,
    const float* __restrict__ rw2, const float* __restrict__ rb2,
    const float* __restrict__ w0, const float* __restrict__ b0,
    const float* __restrict__ lnaw, const float* __restrict__ lnab,
    const float* __restrict__ adot,
    float* __restrict__ ws_attn, float* __restrict__ ws_apre)
{
  // reg2: sb[16*128] (stages 2-3)  then x0t[384*16] (stages 4-5)
  // reg1: xe[16*320] (stages 1-2)  then rbuf[16*385] (stages 3-4)
  __shared__ __align__(16) float reg2[6144];
  __shared__ __align__(16) float reg1[6160];
  __shared__ float wgs[432];
  __shared__ int sidx[16], tidx[16], ansh[16], anth[16];

  const int tid = threadIdx.x;
  const int e0 = blockIdx.x * 16;

  if (tid < 16) {
    int s = eidx[e0 + tid], t = eidx[E_CNT + e0 + tid];
    sidx[tid] = s; tidx[tid] = t; ansh[tid] = an[s]; anth[tid] = an[t];
  }
  for (int i = tid; i < 432; i += 256) {
    int e = i / 27, r = i % 27, kk = r / 9, j = r % 9;
    int row = (kk == 0) ? 0 : (kk == 1 ? 2 : 6);
    wgs[i] = wigner[(size_t)(e0 + e) * 81 + row * 9 + j];
  }
  __syncthreads();

  // stage 1: gather x_edge -> xe (reg1)
  float* xe = reg1;
  for (int i = tid; i < 16 * 320; i += 256) {
    int e = i / 320, c = i % 320;
    float v;
    if (c < 64)       v = edist[(size_t)(e0 + e) * 64 + c];
    else if (c < 192) v = semb[ansh[e] * 128 + (c - 64)];
    else              v = temb[anth[e] * 128 + (c - 192)];
    xe[e * 320 + c] = v;
  }
  __syncthreads();

  // stage 2: [16,320] @ rad_w1[320,128] + b1 -> sb (reg2)
  float* sb = reg2;
  {
    int col = tid & 127, half = tid >> 7;
    const float* wp = rw1 + col;
    float acc[8] = {0, 0, 0, 0, 0, 0, 0, 0};
    float wb[8], nb[8];
#pragma unroll
    for (int i = 0; i < 8; ++i) wb[i] = wp[i * 128];
    for (int kb = 0; kb < 320; kb += 8) {
      if (kb < 312) {
#pragma unroll
        for (int i = 0; i < 8; ++i) nb[i] = wp[(kb + 8 + i) * 128];
      }
#pragma unroll
      for (int i = 0; i < 8; ++i) {
        const float* xr = xe + (half * 8 + i) * 320 + kb;
        float4 a0 = *(const float4*)xr;
        float4 a1 = *(const float4*)(xr + 4);
        acc[i] += a0.x * wb[0] + a0.y * wb[1] + a0.z * wb[2] + a0.w * wb[3]
                + a1.x * wb[4] + a1.y * wb[5] + a1.z * wb[6] + a1.w * wb[7];
      }
#pragma unroll
      for (int i = 0; i < 8; ++i) wb[i] = nb[i];
    }
    float bb = rb1[col];
#pragma unroll
    for (int i = 0; i < 8; ++i) sb[(half * 8 + i) * 128 + col] = acc[i] + bb;
  }
  __syncthreads();

  // stage 2b: LayerNorm(128) + scaled_silu in sb
  {
    int wid = tid >> 6, lane = tid & 63;
    for (int e = wid; e < 16; e += 4) {
      float v0 = sb[e * 128 + lane], v1 = sb[e * 128 + lane + 64];
      float s1 = v0 + v1, s2 = v0 * v0 + v1 * v1;
#pragma unroll
      for (int m = 32; m >= 1; m >>= 1) {
        s1 += __shfl_xor(s1, m);
        s2 += __shfl_xor(s2, m);
      }
      float mu = s1 * (1.f / 128.f);
      float var = s2 * (1.f / 128.f) - mu * mu;
      float rstd = rsqrtf(var + 1e-5f);
      float y0 = (v0 - mu) * rstd * rlnw[lane] + rlnb[lane];
      float y1 = (v1 - mu) * rstd * rlnw[lane + 64] + rlnb[lane + 64];
      sb[e * 128 + lane]      = y0 * sigmoidf_(y0) * (1.f / 0.6f);
      sb[e * 128 + lane + 64] = y1 * sigmoidf_(y1) * (1.f / 0.6f);
    }
  }
  __syncthreads();

  // stage 3: [16,128] @ rad_w2[:, :384] + b2 -> rbuf (reg1; xe dead)
  float* rbuf = reg1;
  {
    int col128 = tid & 127, half = tid >> 7;
    for (int cc = 0; cc < 3; ++cc) {
      int col = cc * 128 + col128;
      const float* wp = rw2 + col;
      float acc[8] = {0, 0, 0, 0, 0, 0, 0, 0};
      float wb[8], nb[8];
#pragma unroll
      for (int i = 0; i < 8; ++i) wb[i] = wp[i * 768];
      for (int kb = 0; kb < 128; kb += 8) {
        if (kb < 120) {
#pragma unroll
          for (int i = 0; i < 8; ++i) nb[i] = wp[(kb + 8 + i) * 768];
        }
#pragma unroll
        for (int i = 0; i < 8; ++i) {
          const float* sr = sb + (half * 8 + i) * 128 + kb;
          float4 a0 = *(const float4*)sr;
          float4 a1 = *(const float4*)(sr + 4);
          acc[i] += a0.x * wb[0] + a0.y * wb[1] + a0.z * wb[2] + a0.w * wb[3]
                  + a1.x * wb[4] + a1.y * wb[5] + a1.z * wb[6] + a1.w * wb[7];
        }
#pragma unroll
        for (int i = 0; i < 8; ++i) wb[i] = nb[i];
      }
      float bb = rb2[col];
#pragma unroll
      for (int i = 0; i < 8; ++i) rbuf[(half * 8 + i) * 385 + col] = acc[i] + bb;
    }
  }
  __syncthreads();

  // stage 4: wigner rows {0,2,6} x cat(x_src,x_tgt), scale by r -> x0t (reg2)
  float* x0t = reg2;
  {
    int e = tid & 15, cg = tid >> 4;
    int c0 = cg * 8;
    const float* xb = (c0 < 64) ? (x + (size_t)sidx[e] * 576 + c0)
                                : (x + (size_t)tidx[e] * 576 + (c0 - 64));
    float xc[9][8];
#pragma unroll
    for (int j = 0; j < 9; ++j) {
      float4 u0 = *(const float4*)(xb + j * 64);
      float4 u1 = *(const float4*)(xb + j * 64 + 4);
      xc[j][0] = u0.x; xc[j][1] = u0.y; xc[j][2] = u0.z; xc[j][3] = u0.w;
      xc[j][4] = u1.x; xc[j][5] = u1.y; xc[j][6] = u1.z; xc[j][7] = u1.w;
    }
#pragma unroll
    for (int kk = 0; kk < 3; ++kk) {
      float wv[9];
#pragma unroll
      for (int j = 0; j < 9; ++j) wv[j] = wgs[e * 27 + kk * 9 + j];
#pragma unroll
      for (int cu = 0; cu < 8; ++cu) {
        float m = 0.f;
#pragma unroll
        for (int j = 0; j < 9; ++j) m += wv[j] * xc[j][cu];
        int colc = kk * 128 + c0 + cu;
        x0t[colc * 16 + e] = m * rbuf[e * 385 + colc];
      }
    }
  }
  __syncthreads();

  // stage 5: [16,384] @ c1_wm0[:, :576] + b — three sequential passes
  {
    float acc[16];
    // pass A: cols 0..255 -> heads (LN32 + smooth_leaky + alpha_dot)
    k1_gemm(x0t, w0 + tid, acc);
    {
      float bb = b0[tid];
      int h = tid >> 5, kk = tid & 31;
      float lw = lnaw[kk], lb = lnab[kk], ad = adot[h * 32 + kk];
#pragma unroll
      for (int e = 0; e < 16; ++e) {
        float v = acc[e] + bb;
        float s1 = v, s2 = v * v;
#pragma unroll
        for (int m = 16; m >= 1; m >>= 1) {
          s1 += __shfl_xor(s1, m);
          s2 += __shfl_xor(s2, m);
        }
        float mu = s1 * (1.f / 32.f);
        float var = s2 * (1.f / 32.f) - mu * mu;
        float rstd = rsqrtf(var + 1e-5f);
        float xn = (v - mu) * rstd * lw + lb;
        float sl = 0.6f * xn + 0.4f * xn * (2.f * sigmoidf_(xn) - 1.f);
        float p = sl * ad;
#pragma unroll
        for (int m = 16; m >= 1; m >>= 1) p += __shfl_xor(p, m);
        if (kk == 0) ws_apre[(size_t)(e0 + e) * 8 + h] = p;
      }
    }
    // pass B: cols 256..511 -> attn_out[0..255]
    k1_gemm(x0t, w0 + 256 + tid, acc);
    {
      float bb = b0[256 + tid];
#pragma unroll
      for (int e = 0; e < 16; ++e)
        ws_attn[(size_t)(e0 + e) * 320 + tid] = acc[e] + bb;
    }
    // pass C: cols 512..575 (wave 0 only)
    if (tid < 64) {
      k1_gemm(x0t, w0 + 512 + tid, acc);
      float bb = b0[512 + tid];
#pragma unroll
      for (int e = 0; e < 16; ++e)
        ws_attn[(size_t)(e0 + e) * 320 + 256 + tid] = acc[e] + bb;
    }
  }
}

// ---------------------------------------------------------------------------
// segment max / exp-sum for softmax over tgt
// ---------------------------------------------------------------------------
__global__ __launch_bounds__(256) void k_segmax(const float* __restrict__ apre,
                                                const int* __restrict__ eidx,
                                                unsigned* __restrict__ segk) {
  int idx = blockIdx.x * 256 + threadIdx.x;
  if (idx >= E_CNT * 8) return;
  int e = idx >> 3, h = idx & 7;
  int t = eidx[E_CNT + e];
  atomicMax(&segk[t * 8 + h], fkey(apre[idx]));
}

__global__ __launch_bounds__(256) void k_expsum(const float* __restrict__ apre,
                                                const int* __restrict__ eidx,
                                                const unsigned* __restrict__ segk,
                                                float* __restrict__ ex_out,
                                                float* __restrict__ denom) {
  int idx = blockIdx.x * 256 + threadIdx.x;
  if (idx >= E_CNT * 8) return;
  int e = idx >> 3, h = idx & 7;
  int t = eidx[E_CNT + e];
  float m = unfkey(segk[t * 8 + h]);
  float ex = __expf(apre[idx] - m);
  ex_out[idx] = ex;
  atomicAdd(&denom[t * 8 + h], ex);
}

// ---------------------------------------------------------------------------
// Phase 2 (round-1 structure, ob-buffer removed): gates, message assembly,
// so2_conv2, alpha scale, wigner_inv, atomic scatter. 16 edges/block.
// ---------------------------------------------------------------------------
__global__ __launch_bounds__(256, 2) void k_phase2(
    const float* __restrict__ x, const int* __restrict__ eidx,
    const float* __restrict__ t_ij, const float* __restrict__ rl_ij,
    const float* __restrict__ winv,
    const float* __restrict__ gwh, const float* __restrict__ gwx, const float* __restrict__ gwt,
    const float* __restrict__ w0, const float* __restrict__ b0,
    const float* __restrict__ w1, const float* __restrict__ w2,
    const float* __restrict__ ws_attn, const float* __restrict__ ws_ex,
    const float* __restrict__ denom,
    float* __restrict__ node)
{
  __shared__ __align__(16) float msg[16 * 576];
  __shared__ float wib[16 * 81];
  __shared__ float alp[16 * 8];
  __shared__ float rlb[16 * 8];
  __shared__ float malp[16];
  __shared__ int tnode[16];

  const int tid = threadIdx.x;
  const int e0 = blockIdx.x * 16;

  if (tid < 16) tnode[tid] = eidx[E_CNT + e0 + tid];
  __syncthreads();

  if (tid < 128) {
    int e = tid >> 3, h = tid & 7;
    float ex = ws_ex[(size_t)(e0 + e) * 8 + h];
    alp[tid] = ex / (denom[tnode[e] * 8 + h] + 1e-16f);
  } else {
    int i = tid - 128;
    int e = i >> 3;
    rlb[i] = rl_ij[(size_t)(e0 + e) * 8 + (i & 7)];
  }
  for (int i = tid; i < 16 * 81; i += 256) {
    int e = i / 81, r = i % 81;
    wib[i] = winv[(size_t)(e0 + e) * 81 + r];
  }
  // stage x[tgt] into msg (h_j row 0, X_j rows 1..8)
  for (int i = tid; i < 16 * 576; i += 256) {
    int e = i / 576, c = i % 576;
    msg[i] = x[(size_t)tnode[e] * 576 + c];
  }
  __syncthreads();
  if (tid < 16) {
    float s = 0.f;
#pragma unroll
    for (int h = 0; h < 8; ++h) s += alp[tid * 8 + h];
    malp[tid] = s * 0.125f;
  }
  __syncthreads();

  // gates: h = silu(h_j @ gwh), tp = silu(t_ij @ gwt), Xp = X_j @ gwx; rebuild msg
  {
    int d = tid & 63, wid = tid >> 6;
    float acch[4] = {0.f, 0.f, 0.f, 0.f}, acct[4] = {0.f, 0.f, 0.f, 0.f};
#pragma unroll 4
    for (int k = 0; k < 64; ++k) {
      float w = gwh[k * 64 + d];
#pragma unroll
      for (int i = 0; i < 4; ++i) acch[i] += msg[(wid * 4 + i) * 576 + k] * w;
    }
#pragma unroll 4
    for (int k = 0; k < 128; ++k) {
      float w = gwt[k * 64 + d];
#pragma unroll
      for (int i = 0; i < 4; ++i) acct[i] += t_ij[(size_t)(e0 + wid * 4 + i) * 128 + k] * w;
    }
    float xp[4][8];
#pragma unroll
    for (int i = 0; i < 4; ++i)
#pragma unroll
      for (int k8 = 0; k8 < 8; ++k8) xp[i][k8] = 0.f;
#pragma unroll 2
    for (int c = 0; c < 64; ++c) {
      float w = gwx[c * 64 + d];
#pragma unroll
      for (int i = 0; i < 4; ++i) {
#pragma unroll
        for (int k8 = 0; k8 < 8; ++k8)
          xp[i][k8] += msg[(wid * 4 + i) * 576 + (k8 + 1) * 64 + c] * w;
      }
    }
    __syncthreads();   // all reads of staged x[tgt] complete before overwrite
#pragma unroll
    for (int i = 0; i < 4; ++i) {
      int e = wid * 4 + i;
      float ml = malp[e];
      const float* wsb = ws_attn + (size_t)(e0 + e) * 320;
      float hv = acch[i]; hv = hv * sigmoidf_(hv);
      float tv = acct[i]; tv = tv * sigmoidf_(tv);
      float os  = wsb[d] * ml;
      float od0 = wsb[64 + d] * ml,  od1 = wsb[128 + d] * ml;
      float ot0 = wsb[192 + d] * ml, ot1 = wsb[256 + d] * ml;
      msg[e * 576 + d] = os * hv;
#pragma unroll
      for (int j = 0; j < 3; ++j)
        msg[e * 576 + (1 + j) * 64 + d] = od0 * xp[i][j] + ot0 * tv * rlb[e * 8 + j];
#pragma unroll
      for (int j = 0; j < 5; ++j)
        msg[e * 576 + (4 + j) * 64 + d] = od1 * xp[i][3 + j] + ot1 * tv * rlb[e * 8 + 3 + j];
    }
  }
  __syncthreads();

  // so2_conv2 (per output channel c), alpha scale, wigner_inv, atomic scatter
  {
    int c = tid & 127, eh = tid >> 7;
    const int ebase = eh * 8;
    float m2[9][8];
    {  // wm0: x0 = msg rows {0,2,6}
      float a0[3][8];
#pragma unroll
      for (int q = 0; q < 3; ++q)
#pragma unroll
        for (int ee = 0; ee < 8; ++ee) a0[q][ee] = 0.f;
#pragma unroll 2
      for (int k = 0; k < 192; ++k) {
        int row = (k < 64) ? 0 : ((k < 128) ? 2 : 6);
        int src = row * 64 + (k & 63);
        float wA = w0[k * 384 + c];
        float wB = w0[k * 384 + 128 + c];
        float wC = w0[k * 384 + 256 + c];
#pragma unroll
        for (int ee = 0; ee < 8; ++ee) {
          float a = msg[(ebase + ee) * 576 + src];
          a0[0][ee] += a * wA; a0[1][ee] += a * wB; a0[2][ee] += a * wC;
        }
      }
      float bA = b0[c], bB = b0[128 + c], bC = b0[256 + c];
#pragma unroll
      for (int ee = 0; ee < 8; ++ee) {
        m2[0][ee] = a0[0][ee] + bA;
        m2[2][ee] = a0[1][ee] + bB;
        m2[6][ee] = a0[2][ee] + bC;
      }
    }
    {  // wm1: x1 rows [3|7] and [1|5]
      float y0[4][8], y1[4][8];
#pragma unroll
      for (int q = 0; q < 4; ++q)
#pragma unroll
        for (int ee = 0; ee < 8; ++ee) { y0[q][ee] = 0.f; y1[q][ee] = 0.f; }
#pragma unroll 2
      for (int k = 0; k < 128; ++k) {
        int s0 = (k < 64) ? (3 * 64 + k) : (7 * 64 + k - 64);
        int s1 = (k < 64) ? (1 * 64 + k) : (5 * 64 + k - 64);
        float wA = w1[k * 512 + c],       wB = w1[k * 512 + 128 + c];
        float wC = w1[k * 512 + 256 + c], wD = w1[k * 512 + 384 + c];
#pragma unroll
        for (int ee = 0; ee < 8; ++ee) {
          float aa = msg[(ebase + ee) * 576 + s0];
          float ab = msg[(ebase + ee) * 576 + s1];
          y0[0][ee] += aa * wA; y0[1][ee] += aa * wB; y0[2][ee] += aa * wC; y0[3][ee] += aa * wD;
          y1[0][ee] += ab * wA; y1[1][ee] += ab * wB; y1[2][ee] += ab * wC; y1[3][ee] += ab * wD;
        }
      }
#pragma unroll
      for (int ee = 0; ee < 8; ++ee) {
        m2[3][ee] = y0[0][ee] - y1[2][ee];
        m2[7][ee] = y0[1][ee] - y1[3][ee];
        m2[1][ee] = y1[0][ee] + y0[2][ee];
        m2[5][ee] = y1[1][ee] + y0[3][ee];
      }
    }
    {  // wm2: x2 rows 8 and 4
      float z0[2][8], z1[2][8];
#pragma unroll
      for (int q = 0; q < 2; ++q)
#pragma unroll
        for (int ee = 0; ee < 8; ++ee) { z0[q][ee] = 0.f; z1[q][ee] = 0.f; }
#pragma unroll 2
      for (int k = 0; k < 64; ++k) {
        float wA = w2[k * 256 + c], wB = w2[k * 256 + 128 + c];
#pragma unroll
        for (int ee = 0; ee < 8; ++ee) {
          float aa = msg[(ebase + ee) * 576 + 8 * 64 + k];
          float ab = msg[(ebase + ee) * 576 + 4 * 64 + k];
          z0[0][ee] += aa * wA; z0[1][ee] += aa * wB;
          z1[0][ee] += ab * wA; z1[1][ee] += ab * wB;
        }
      }
#pragma unroll
      for (int ee = 0; ee < 8; ++ee) {
        m2[8][ee] = z0[0][ee] - z1[1][ee];
        m2[4][ee] = z1[0][ee] + z0[1][ee];
      }
    }
    // alpha scale + wigner_inv + atomicAdd into node
    int h = c >> 4;
#pragma unroll
    for (int ee = 0; ee < 8; ++ee) {
      int e = ebase + ee;
      float av = alp[e * 8 + h];
      float mm[9];
#pragma unroll
      for (int j = 0; j < 9; ++j) mm[j] = m2[j][ee] * av;
      float* np = node + (size_t)tnode[e] * 1152 + c;
#pragma unroll
      for (int i = 0; i < 9; ++i) {
        float s = 0.f;
#pragma unroll
        for (int j = 0; j < 9; ++j) s += wib[e * 81 + i * 9 + j] * mm[j];
        atomicAdd(np + i * 128, s);
      }
    }
  }
}

// ---------------------------------------------------------------------------
// proj_w transpose + per-node projection
// ---------------------------------------------------------------------------
__global__ __launch_bounds__(256) void k_wt(const float* __restrict__ pw, float* __restrict__ wT) {
  int idx = blockIdx.x * 256 + threadIdx.x;
  if (idx >= 3 * 128 * 64) return;
  int l = idx / 8192, r = idx % 8192, i = r / 64, o = r % 64;
  wT[idx] = pw[(l * 64 + o) * 128 + i];
}

__global__ __launch_bounds__(256) void k_proj(const float* __restrict__ node,
                                              const float* __restrict__ wT,
                                              const float* __restrict__ pb,
                                              float* __restrict__ out) {
  __shared__ __align__(16) float A[32 * 132];
  int k = blockIdx.y;
  int n0 = blockIdx.x * 32;
  const int lidx = (k == 0) ? 0 : (k <= 3 ? 1 : 2);
  int tid = threadIdx.x;
  for (int i = tid; i < 32 * 128; i += 256) {
    int nn = i >> 7, ii = i & 127;
    int n = n0 + nn;
    A[nn * 132 + ii] = (n < N_NODES) ? node[((size_t)n * 9 + k) * 128 + ii] : 0.f;
  }
  __syncthreads();
  int o = tid & 63, wid = tid >> 6;
  float acc[8] = {0.f, 0.f, 0.f, 0.f, 0.f, 0.f, 0.f, 0.f};
  const float* wp = wT + lidx * 8192 + o;
  float wb[8], nb[8];
#pragma unroll
  for (int i = 0; i < 8; ++i) wb[i] = wp[i * 64];
  for (int ib = 0; ib < 128; ib += 8) {
    if (ib < 120) {
#pragma unroll
      for (int i = 0; i < 8; ++i) nb[i] = wp[(ib + 8 + i) * 64];
    }
#pragma unroll
    for (int r = 0; r < 8; ++r) {
      const float* ar = &A[(wid * 8 + r) * 132 + ib];
      float4 a0 = *(const float4*)ar;
      float4 a1 = *(const float4*)(ar + 4);
      acc[r] += a0.x * wb[0] + a0.y * wb[1] + a0.z * wb[2] + a0.w * wb[3]
              + a1.x * wb[4] + a1.y * wb[5] + a1.z * wb[6] + a1.w * wb[7];
    }
#pragma unroll
    for (int i = 0; i < 8; ++i) wb[i] = nb[i];
  }
  float bias = (k == 0) ? pb[o] : 0.f;
#pragma unroll
  for (int r = 0; r < 8; ++r) {
    int n = n0 + wid * 8 + r;
    if (n < N_NODES) out[((size_t)n * 9 + k) * 64 + o] = acc[r] + bias;
  }
}

// ---------------------------------------------------------------------------
extern "C" void kernel_launch(void* const* d_in, const int* in_sizes, int n_in,
                              void* d_out, int out_size, void* d_ws, size_t ws_size,
                              hipStream_t stream) {
  const float* x      = (const float*)d_in[0];
  const int*   an     = (const int*)d_in[1];
  const float* edist  = (const float*)d_in[2];
  const int*   eidx   = (const int*)d_in[3];
  const float* t_ij   = (const float*)d_in[4];
  const float* rl_ij  = (const float*)d_in[5];
  const float* wig    = (const float*)d_in[6];
  const float* winv   = (const float*)d_in[7];
  const float* semb   = (const float*)d_in[8];
  const float* temb   = (const float*)d_in[9];
  const float* rw1    = (const float*)d_in[10];
  const float* rb1    = (const float*)d_in[11];
  const float* rlnw   = (const float*)d_in[12];
  const float* rlnb   = (const float*)d_in[13];
  const float* rw2    = (const float*)d_in[14];
  const float* rb2    = (const float*)d_in[15];
  const float* c1w0   = (const float*)d_in[16];
  const float* c1b0   = (const float*)d_in[17];
  // d_in[18], d_in[19]: c1_wm1 / c1_wm2 — dead code in the reference
  const float* lnaw   = (const float*)d_in[20];
  const float* lnab   = (const float*)d_in[21];
  const float* adot   = (const float*)d_in[22];
  const float* gwh    = (const float*)d_in[23];
  const float* gwx    = (const float*)d_in[24];
  const float* gwt    = (const float*)d_in[25];
  const float* c2w0   = (const float*)d_in[26];
  const float* c2b0   = (const float*)d_in[27];
  const float* c2w1   = (const float*)d_in[28];
  const float* c2w2   = (const float*)d_in[29];
  const float* pw     = (const float*)d_in[30];
  const float* pb     = (const float*)d_in[31];
  float* out = (float*)d_out;

  char* p = (char*)d_ws;
  float* ws_attn  = (float*)p; p += (size_t)E_CNT * 320 * 4;
  float* ws_apre  = (float*)p; p += (size_t)E_CNT * 8 * 4;
  float* ws_ex    = (float*)p; p += (size_t)E_CNT * 8 * 4;
  unsigned* segk  = (unsigned*)p; p += (size_t)N_NODES * 8 * 4;
  float* denom    = (float*)p; p += (size_t)N_NODES * 8 * 4;
  float* node     = (float*)p; p += (size_t)N_NODES * 1152 * 4;
  float* wT       = (float*)p; p += (size_t)3 * 128 * 64 * 4;

  hipMemsetAsync(segk, 0, N_NODES * 8 * 4, stream);
  hipMemsetAsync(denom, 0, N_NODES * 8 * 4, stream);
  hipMemsetAsync(node, 0, (size_t)N_NODES * 1152 * 4, stream);

  k_wt<<<96, 256, 0, stream>>>(pw, wT);
  k_phase1<<<E_CNT / 16, 256, 0, stream>>>(x, an, edist, eidx, wig, semb, temb,
                                           rw1, rb1, rlnw, rlnb, rw2, rb2,
                                           c1w0, c1b0, lnaw, lnab, adot,
                                           ws_attn, ws_apre);
  k_segmax<<<(E_CNT * 8) / 256, 256, 0, stream>>>(ws_apre, eidx, segk);
  k_expsum<<<(E_CNT * 8) / 256, 256, 0, stream>>>(ws_apre, eidx, segk, ws_ex, denom);
  k_phase2<<<E_CNT / 16, 256, 0, stream>>>(x, eidx, t_ij, rl_ij, winv,
                                           gwh, gwx, gwt, c2w0, c2b0, c2w1, c2w2,
                                           ws_attn, ws_ex, denom, node);
  k_proj<<<dim3((N_NODES + 31) / 32, 9), 256, 0, stream>>>(node, wT, pb, out);
}

// Round 4
// 2522.144 us; speedup vs baseline: 3.3288x; 3.3288x over previous
//
#include <hip/hip_runtime.h>

#define E_CNT 80000
#define N_NODES 10000

__device__ __forceinline__ float sigmoidf_(float x) { return 1.f / (1.f + __expf(-x)); }

__device__ __forceinline__ unsigned fkey(float f) {
  unsigned u = __float_as_uint(f);
  return (u & 0x80000000u) ? ~u : (u | 0x80000000u);
}
__device__ __forceinline__ float unfkey(unsigned k) {
  unsigned u = (k & 0x80000000u) ? (k & 0x7FFFFFFFu) : ~k;
  return __uint_as_float(u);
}

// ---------------------------------------------------------------------------
// Phase 1. 16 edges/block, 256 threads, 3 blocks/CU (LDS 50 KB).
// R1-style loop bodies (plain loads; NO manual prefetch arrays — they spill).
// ---------------------------------------------------------------------------

__device__ __forceinline__ void k1_gemm3(const float* x0t, const float* __restrict__ w0,
                                         int col, float acc[16]) {
  const float4* x4 = (const float4*)x0t;
#pragma unroll
  for (int i = 0; i < 16; ++i) acc[i] = 0.f;
#pragma unroll 4
  for (int k = 0; k < 384; ++k) {
    float w = w0[(size_t)k * 768 + col];
    float4 a0 = x4[k * 4 + 0];
    float4 a1 = x4[k * 4 + 1];
    float4 a2 = x4[k * 4 + 2];
    float4 a3 = x4[k * 4 + 3];
    acc[0]  += a0.x * w; acc[1]  += a0.y * w; acc[2]  += a0.z * w; acc[3]  += a0.w * w;
    acc[4]  += a1.x * w; acc[5]  += a1.y * w; acc[6]  += a1.z * w; acc[7]  += a1.w * w;
    acc[8]  += a2.x * w; acc[9]  += a2.y * w; acc[10] += a2.z * w; acc[11] += a2.w * w;
    acc[12] += a3.x * w; acc[13] += a3.y * w; acc[14] += a3.z * w; acc[15] += a3.w * w;
  }
}

__global__ __launch_bounds__(256, 3) void k_phase1(
    const float* __restrict__ x, const int* __restrict__ an,
    const float* __restrict__ edist, const int* __restrict__ eidx,
    const float* __restrict__ wigner,
    const float* __restrict__ semb, const float* __restrict__ temb,
    const float* __restrict__ rw1, const float* __restrict__ rb1,
    const float* __restrict__ rlnw, const float* __restrict__ rlnb,
    const float* __restrict__ rw2, const float* __restrict__ rb2,
    const float* __restrict__ w0, const float* __restrict__ b0,
    const float* __restrict__ lnaw, const float* __restrict__ lnab,
    const float* __restrict__ adot,
    float* __restrict__ ws_attn, float* __restrict__ ws_apre)
{
  // reg2: sb[16*128] (stages 2-3)  then x0t[384*16] (stages 4-5)
  // reg1: xe[16*320] (stages 1-2)  then rbuf[16*385] (stages 3-4)
  __shared__ __align__(16) float reg2[6144];
  __shared__ __align__(16) float reg1[6160];
  __shared__ float wgs[432];
  __shared__ int sidx[16], tidx[16], ansh[16], anth[16];

  const int tid = threadIdx.x;
  const int e0 = blockIdx.x * 16;

  if (tid < 16) {
    int s = eidx[e0 + tid], t = eidx[E_CNT + e0 + tid];
    sidx[tid] = s; tidx[tid] = t; ansh[tid] = an[s]; anth[tid] = an[t];
  }
  for (int i = tid; i < 432; i += 256) {
    int e = i / 27, r = i % 27, kk = r / 9, j = r % 9;
    int row = (kk == 0) ? 0 : (kk == 1 ? 2 : 6);
    wgs[i] = wigner[(size_t)(e0 + e) * 81 + row * 9 + j];
  }
  __syncthreads();

  // stage 1: gather x_edge -> xe (reg1)
  float* xe = reg1;
  for (int i = tid; i < 16 * 320; i += 256) {
    int e = i / 320, c = i % 320;
    float v;
    if (c < 64)       v = edist[(size_t)(e0 + e) * 64 + c];
    else if (c < 192) v = semb[ansh[e] * 128 + (c - 64)];
    else              v = temb[anth[e] * 128 + (c - 192)];
    xe[e * 320 + c] = v;
  }
  __syncthreads();

  // stage 2: [16,320] @ rad_w1[320,128] + b1 -> sb (reg2)
  float* sb = reg2;
  {
    int col = tid & 127, half = tid >> 7;
    float acc[8];
#pragma unroll
    for (int i = 0; i < 8; ++i) acc[i] = 0.f;
#pragma unroll 4
    for (int k = 0; k < 320; ++k) {
      float w = rw1[k * 128 + col];
#pragma unroll
      for (int i = 0; i < 8; ++i) acc[i] += xe[(half * 8 + i) * 320 + k] * w;
    }
    float bb = rb1[col];
#pragma unroll
    for (int i = 0; i < 8; ++i) sb[(half * 8 + i) * 128 + col] = acc[i] + bb;
  }
  __syncthreads();

  // stage 2b: LayerNorm(128) + scaled_silu in sb
  {
    int wid = tid >> 6, lane = tid & 63;
    for (int e = wid; e < 16; e += 4) {
      float v0 = sb[e * 128 + lane], v1 = sb[e * 128 + lane + 64];
      float s1 = v0 + v1, s2 = v0 * v0 + v1 * v1;
#pragma unroll
      for (int m = 32; m >= 1; m >>= 1) {
        s1 += __shfl_xor(s1, m);
        s2 += __shfl_xor(s2, m);
      }
      float mu = s1 * (1.f / 128.f);
      float var = s2 * (1.f / 128.f) - mu * mu;
      float rstd = rsqrtf(var + 1e-5f);
      float y0 = (v0 - mu) * rstd * rlnw[lane] + rlnb[lane];
      float y1 = (v1 - mu) * rstd * rlnw[lane + 64] + rlnb[lane + 64];
      sb[e * 128 + lane]      = y0 * sigmoidf_(y0) * (1.f / 0.6f);
      sb[e * 128 + lane + 64] = y1 * sigmoidf_(y1) * (1.f / 0.6f);
    }
  }
  __syncthreads();

  // stage 3: [16,128] @ rad_w2[:, :384] + b2 -> rbuf (reg1; xe dead)
  float* rbuf = reg1;
  {
    int col128 = tid & 127, half = tid >> 7;
    for (int cc = 0; cc < 3; ++cc) {
      int col = cc * 128 + col128;
      float acc[8];
#pragma unroll
      for (int i = 0; i < 8; ++i) acc[i] = 0.f;
#pragma unroll 4
      for (int k = 0; k < 128; ++k) {
        float w = rw2[k * 768 + col];
#pragma unroll
        for (int i = 0; i < 8; ++i) acc[i] += sb[(half * 8 + i) * 128 + k] * w;
      }
      float bb = rb2[col];
#pragma unroll
      for (int i = 0; i < 8; ++i) rbuf[(half * 8 + i) * 385 + col] = acc[i] + bb;
    }
  }
  __syncthreads();

  // stage 4: wigner rows {0,2,6} x cat(x_src,x_tgt), scale by r -> x0t (reg2)
  float* x0t = reg2;
  {
    int e = tid & 15, cg = tid >> 4;
    int c0 = cg * 8;
    const float* xb = (c0 < 64) ? (x + (size_t)sidx[e] * 576 + c0)
                                : (x + (size_t)tidx[e] * 576 + (c0 - 64));
    float xc[9][8];
#pragma unroll
    for (int j = 0; j < 9; ++j) {
      float4 u0 = *(const float4*)(xb + j * 64);
      float4 u1 = *(const float4*)(xb + j * 64 + 4);
      xc[j][0] = u0.x; xc[j][1] = u0.y; xc[j][2] = u0.z; xc[j][3] = u0.w;
      xc[j][4] = u1.x; xc[j][5] = u1.y; xc[j][6] = u1.z; xc[j][7] = u1.w;
    }
#pragma unroll
    for (int kk = 0; kk < 3; ++kk) {
      float wv[9];
#pragma unroll
      for (int j = 0; j < 9; ++j) wv[j] = wgs[e * 27 + kk * 9 + j];
#pragma unroll
      for (int cu = 0; cu < 8; ++cu) {
        float m = 0.f;
#pragma unroll
        for (int j = 0; j < 9; ++j) m += wv[j] * xc[j][cu];
        int colc = kk * 128 + c0 + cu;
        x0t[colc * 16 + e] = m * rbuf[e * 385 + colc];
      }
    }
  }
  __syncthreads();

  // stage 5: [16,384] @ c1_wm0[:, :576] + b — three sequential passes
  {
    float acc[16];
    // pass A: cols 0..255 -> heads (LN32 + smooth_leaky + alpha_dot)
    k1_gemm3(x0t, w0, tid, acc);
    {
      float bb = b0[tid];
      int h = tid >> 5, kk = tid & 31;
      float lw = lnaw[kk], lb = lnab[kk], ad = adot[h * 32 + kk];
#pragma unroll
      for (int e = 0; e < 16; ++e) {
        float v = acc[e] + bb;
        float s1 = v, s2 = v * v;
#pragma unroll
        for (int m = 16; m >= 1; m >>= 1) {
          s1 += __shfl_xor(s1, m);
          s2 += __shfl_xor(s2, m);
        }
        float mu = s1 * (1.f / 32.f);
        float var = s2 * (1.f / 32.f) - mu * mu;
        float rstd = rsqrtf(var + 1e-5f);
        float xn = (v - mu) * rstd * lw + lb;
        float sl = 0.6f * xn + 0.4f * xn * (2.f * sigmoidf_(xn) - 1.f);
        float p = sl * ad;
#pragma unroll
        for (int m = 16; m >= 1; m >>= 1) p += __shfl_xor(p, m);
        if (kk == 0) ws_apre[(size_t)(e0 + e) * 8 + h] = p;
      }
    }
    // pass B: cols 256..511 -> attn_out[0..255]
    k1_gemm3(x0t, w0, 256 + tid, acc);
    {
      float bb = b0[256 + tid];
#pragma unroll
      for (int e = 0; e < 16; ++e)
        ws_attn[(size_t)(e0 + e) * 320 + tid] = acc[e] + bb;
    }
    // pass C: cols 512..575 (wave 0 only)
    if (tid < 64) {
      k1_gemm3(x0t, w0, 512 + tid, acc);
      float bb = b0[512 + tid];
#pragma unroll
      for (int e = 0; e < 16; ++e)
        ws_attn[(size_t)(e0 + e) * 320 + 256 + tid] = acc[e] + bb;
    }
  }
}

// ---------------------------------------------------------------------------
// segment max / exp-sum for softmax over tgt
// ---------------------------------------------------------------------------
__global__ __launch_bounds__(256) void k_segmax(const float* __restrict__ apre,
                                                const int* __restrict__ eidx,
                                                unsigned* __restrict__ segk) {
  int idx = blockIdx.x * 256 + threadIdx.x;
  if (idx >= E_CNT * 8) return;
  int e = idx >> 3, h = idx & 7;
  int t = eidx[E_CNT + e];
  atomicMax(&segk[t * 8 + h], fkey(apre[idx]));
}

__global__ __launch_bounds__(256) void k_expsum(const float* __restrict__ apre,
                                                const int* __restrict__ eidx,
                                                const unsigned* __restrict__ segk,
                                                float* __restrict__ ex_out,
                                                float* __restrict__ denom) {
  int idx = blockIdx.x * 256 + threadIdx.x;
  if (idx >= E_CNT * 8) return;
  int e = idx >> 3, h = idx & 7;
  int t = eidx[E_CNT + e];
  float m = unfkey(segk[t * 8 + h]);
  float ex = __expf(apre[idx] - m);
  ex_out[idx] = ex;
  atomicAdd(&denom[t * 8 + h], ex);
}

// ---------------------------------------------------------------------------
// Phase 2 (R1 verbatim): gates, message assembly, so2_conv2, alpha scale,
// wigner_inv, atomic scatter. 16 edges/block, 256 threads.
// ---------------------------------------------------------------------------
__global__ __launch_bounds__(256, 2) void k_phase2(
    const float* __restrict__ x, const int* __restrict__ eidx,
    const float* __restrict__ t_ij, const float* __restrict__ rl_ij,
    const float* __restrict__ winv,
    const float* __restrict__ gwh, const float* __restrict__ gwx, const float* __restrict__ gwt,
    const float* __restrict__ w0, const float* __restrict__ b0,
    const float* __restrict__ w1, const float* __restrict__ w2,
    const float* __restrict__ ws_attn, const float* __restrict__ ws_ex,
    const float* __restrict__ denom,
    float* __restrict__ node)
{
  __shared__ float ob[16 * 320];
  __shared__ __align__(16) float msg[16 * 576];
  __shared__ float wib[16 * 81];
  __shared__ float alp[16 * 8];
  __shared__ float rlb[16 * 8];
  __shared__ float malp[16];
  __shared__ int tnode[16];

  const int tid = threadIdx.x;
  const int e0 = blockIdx.x * 16;

  if (tid < 16) tnode[tid] = eidx[E_CNT + e0 + tid];
  __syncthreads();

  if (tid < 128) {
    int e = tid >> 3, h = tid & 7;
    float ex = ws_ex[(size_t)(e0 + e) * 8 + h];
    alp[tid] = ex / (denom[tnode[e] * 8 + h] + 1e-16f);
  } else {
    int i = tid - 128;
    int e = i >> 3;
    rlb[i] = rl_ij[(size_t)(e0 + e) * 8 + (i & 7)];
  }
  for (int i = tid; i < 16 * 81; i += 256) {
    int e = i / 81, r = i % 81;
    wib[i] = winv[(size_t)(e0 + e) * 81 + r];
  }
  // stage x[tgt] rows 0..8 into msg (as X_j source)
  for (int i = tid; i < 16 * 576; i += 256) {
    int e = i / 576, c = i % 576;
    msg[i] = x[(size_t)tnode[e] * 576 + c];
  }
  __syncthreads();
  if (tid < 16) {
    float s = 0.f;
#pragma unroll
    for (int h = 0; h < 8; ++h) s += alp[tid * 8 + h];
    malp[tid] = s * 0.125f;
  }
  __syncthreads();
  for (int i = tid; i < 16 * 320; i += 256) {
    int e = i / 320;
    ob[i] = malp[e] * ws_attn[(size_t)e0 * 320 + i];
  }
  __syncthreads();

  // gates: h = silu(h_j @ gwh), tp = silu(t_ij @ gwt), Xp = X_j @ gwx; build msg rows
  {
    int d = tid & 63, wid = tid >> 6;
    float acch[4] = {0.f, 0.f, 0.f, 0.f}, acct[4] = {0.f, 0.f, 0.f, 0.f};
#pragma unroll 4
    for (int k = 0; k < 64; ++k) {
      float w = gwh[k * 64 + d];
#pragma unroll
      for (int i = 0; i < 4; ++i) acch[i] += msg[(wid * 4 + i) * 576 + k] * w;
    }
#pragma unroll 4
    for (int k = 0; k < 128; ++k) {
      float w = gwt[k * 64 + d];
#pragma unroll
      for (int i = 0; i < 4; ++i) acct[i] += t_ij[(size_t)(e0 + wid * 4 + i) * 128 + k] * w;
    }
    float xp[4][8];
#pragma unroll
    for (int i = 0; i < 4; ++i)
#pragma unroll
      for (int k8 = 0; k8 < 8; ++k8) xp[i][k8] = 0.f;
#pragma unroll 2
    for (int c = 0; c < 64; ++c) {
      float w = gwx[c * 64 + d];
#pragma unroll
      for (int i = 0; i < 4; ++i) {
#pragma unroll
        for (int k8 = 0; k8 < 8; ++k8)
          xp[i][k8] += msg[(wid * 4 + i) * 576 + (k8 + 1) * 64 + c] * w;
      }
    }
    __syncthreads();   // all reads of staged x[tgt] complete
#pragma unroll
    for (int i = 0; i < 4; ++i) {
      int e = wid * 4 + i;
      float hv = acch[i]; hv = hv * sigmoidf_(hv);
      float tv = acct[i]; tv = tv * sigmoidf_(tv);
      float os  = ob[e * 320 + d];
      float od0 = ob[e * 320 + 64 + d],  od1 = ob[e * 320 + 128 + d];
      float ot0 = ob[e * 320 + 192 + d], ot1 = ob[e * 320 + 256 + d];
      msg[e * 576 + d] = os * hv;
#pragma unroll
      for (int j = 0; j < 3; ++j)
        msg[e * 576 + (1 + j) * 64 + d] = od0 * xp[i][j] + ot0 * tv * rlb[e * 8 + j];
#pragma unroll
      for (int j = 0; j < 5; ++j)
        msg[e * 576 + (4 + j) * 64 + d] = od1 * xp[i][3 + j] + ot1 * tv * rlb[e * 8 + 3 + j];
    }
  }
  __syncthreads();

  // so2_conv2 (per output channel c), alpha scale, wigner_inv, atomic scatter
  {
    int c = tid & 127, eh = tid >> 7;
    const int ebase = eh * 8;
    float m2[9][8];
    {  // wm0: x0 = msg rows {0,2,6}
      float a0[3][8];
#pragma unroll
      for (int q = 0; q < 3; ++q)
#pragma unroll
        for (int ee = 0; ee < 8; ++ee) a0[q][ee] = 0.f;
#pragma unroll 2
      for (int k = 0; k < 192; ++k) {
        int row = (k < 64) ? 0 : ((k < 128) ? 2 : 6);
        int src = row * 64 + (k & 63);
        float wA = w0[k * 384 + c];
        float wB = w0[k * 384 + 128 + c];
        float wC = w0[k * 384 + 256 + c];
#pragma unroll
        for (int ee = 0; ee < 8; ++ee) {
          float a = msg[(ebase + ee) * 576 + src];
          a0[0][ee] += a * wA; a0[1][ee] += a * wB; a0[2][ee] += a * wC;
        }
      }
      float bA = b0[c], bB = b0[128 + c], bC = b0[256 + c];
#pragma unroll
      for (int ee = 0; ee < 8; ++ee) {
        m2[0][ee] = a0[0][ee] + bA;
        m2[2][ee] = a0[1][ee] + bB;
        m2[6][ee] = a0[2][ee] + bC;
      }
    }
    {  // wm1: x1 rows [3|7] and [1|5]
      float y0[4][8], y1[4][8];
#pragma unroll
      for (int q = 0; q < 4; ++q)
#pragma unroll
        for (int ee = 0; ee < 8; ++ee) { y0[q][ee] = 0.f; y1[q][ee] = 0.f; }
#pragma unroll 2
      for (int k = 0; k < 128; ++k) {
        int s0 = (k < 64) ? (3 * 64 + k) : (7 * 64 + k - 64);
        int s1 = (k < 64) ? (1 * 64 + k) : (5 * 64 + k - 64);
        float wA = w1[k * 512 + c],       wB = w1[k * 512 + 128 + c];
        float wC = w1[k * 512 + 256 + c], wD = w1[k * 512 + 384 + c];
#pragma unroll
        for (int ee = 0; ee < 8; ++ee) {
          float aa = msg[(ebase + ee) * 576 + s0];
          float ab = msg[(ebase + ee) * 576 + s1];
          y0[0][ee] += aa * wA; y0[1][ee] += aa * wB; y0[2][ee] += aa * wC; y0[3][ee] += aa * wD;
          y1[0][ee] += ab * wA; y1[1][ee] += ab * wB; y1[2][ee] += ab * wC; y1[3][ee] += ab * wD;
        }
      }
#pragma unroll
      for (int ee = 0; ee < 8; ++ee) {
        m2[3][ee] = y0[0][ee] - y1[2][ee];
        m2[7][ee] = y0[1][ee] - y1[3][ee];
        m2[1][ee] = y1[0][ee] + y0[2][ee];
        m2[5][ee] = y1[1][ee] + y0[3][ee];
      }
    }
    {  // wm2: x2 rows 8 and 4
      float z0[2][8], z1[2][8];
#pragma unroll
      for (int q = 0; q < 2; ++q)
#pragma unroll
        for (int ee = 0; ee < 8; ++ee) { z0[q][ee] = 0.f; z1[q][ee] = 0.f; }
#pragma unroll 2
      for (int k = 0; k < 64; ++k) {
        float wA = w2[k * 256 + c], wB = w2[k * 256 + 128 + c];
#pragma unroll
        for (int ee = 0; ee < 8; ++ee) {
          float aa = msg[(ebase + ee) * 576 + 8 * 64 + k];
          float ab = msg[(ebase + ee) * 576 + 4 * 64 + k];
          z0[0][ee] += aa * wA; z0[1][ee] += aa * wB;
          z1[0][ee] += ab * wA; z1[1][ee] += ab * wB;
        }
      }
#pragma unroll
      for (int ee = 0; ee < 8; ++ee) {
        m2[8][ee] = z0[0][ee] - z1[1][ee];
        m2[4][ee] = z1[0][ee] + z0[1][ee];
      }
    }
    // alpha scale + wigner_inv + atomicAdd into node
    int h = c >> 4;
#pragma unroll
    for (int ee = 0; ee < 8; ++ee) {
      int e = ebase + ee;
      float av = alp[e * 8 + h];
      float mm[9];
#pragma unroll
      for (int j = 0; j < 9; ++j) mm[j] = m2[j][ee] * av;
      float* np = node + (size_t)tnode[e] * 1152 + c;
#pragma unroll
      for (int i = 0; i < 9; ++i) {
        float s = 0.f;
#pragma unroll
        for (int j = 0; j < 9; ++j) s += wib[e * 81 + i * 9 + j] * mm[j];
        atomicAdd(np + i * 128, s);
      }
    }
  }
}

// ---------------------------------------------------------------------------
// proj_w transpose + per-node projection (R1 verbatim)
// ---------------------------------------------------------------------------
__global__ __launch_bounds__(256) void k_wt(const float* __restrict__ pw, float* __restrict__ wT) {
  int idx = blockIdx.x * 256 + threadIdx.x;
  if (idx >= 3 * 128 * 64) return;
  int l = idx / 8192, r = idx % 8192, i = r / 64, o = r % 64;
  wT[idx] = pw[(l * 64 + o) * 128 + i];
}

__global__ __launch_bounds__(256) void k_proj(const float* __restrict__ node,
                                              const float* __restrict__ wT,
                                              const float* __restrict__ pb,
                                              float* __restrict__ out) {
  __shared__ __align__(16) float A[32 * 132];
  int k = blockIdx.y;
  int n0 = blockIdx.x * 32;
  const int lidx = (k == 0) ? 0 : (k <= 3 ? 1 : 2);
  int tid = threadIdx.x;
  for (int i = tid; i < 32 * 128; i += 256) {
    int nn = i >> 7, ii = i & 127;
    int n = n0 + nn;
    A[nn * 132 + ii] = (n < N_NODES) ? node[((size_t)n * 9 + k) * 128 + ii] : 0.f;
  }
  __syncthreads();
  int o = tid & 63, wid = tid >> 6;
  float acc[8] = {0.f, 0.f, 0.f, 0.f, 0.f, 0.f, 0.f, 0.f};
#pragma unroll 4
  for (int i = 0; i < 128; ++i) {
    float w = wT[lidx * 8192 + i * 64 + o];
#pragma unroll
    for (int r = 0; r < 8; ++r) acc[r] += A[(wid * 8 + r) * 132 + i] * w;
  }
  float bias = (k == 0) ? pb[o] : 0.f;
#pragma unroll
  for (int r = 0; r < 8; ++r) {
    int n = n0 + wid * 8 + r;
    if (n < N_NODES) out[((size_t)n * 9 + k) * 64 + o] = acc[r] + bias;
  }
}

// ---------------------------------------------------------------------------
extern "C" void kernel_launch(void* const* d_in, const int* in_sizes, int n_in,
                              void* d_out, int out_size, void* d_ws, size_t ws_size,
                              hipStream_t stream) {
  const float* x      = (const float*)d_in[0];
  const int*   an     = (const int*)d_in[1];
  const float* edist  = (const float*)d_in[2];
  const int*   eidx   = (const int*)d_in[3];
  const float* t_ij   = (const float*)d_in[4];
  const float* rl_ij  = (const float*)d_in[5];
  const float* wig    = (const float*)d_in[6];
  const float* winv   = (const float*)d_in[7];
  const float* semb   = (const float*)d_in[8];
  const float* temb   = (const float*)d_in[9];
  const float* rw1    = (const float*)d_in[10];
  const float* rb1    = (const float*)d_in[11];
  const float* rlnw   = (const float*)d_in[12];
  const float* rlnb   = (const float*)d_in[13];
  const float* rw2    = (const float*)d_in[14];
  const float* rb2    = (const float*)d_in[15];
  const float* c1w0   = (const float*)d_in[16];
  const float* c1b0   = (const float*)d_in[17];
  // d_in[18], d_in[19]: c1_wm1 / c1_wm2 — dead code in the reference
  const float* lnaw   = (const float*)d_in[20];
  const float* lnab   = (const float*)d_in[21];
  const float* adot   = (const float*)d_in[22];
  const float* gwh    = (const float*)d_in[23];
  const float* gwx    = (const float*)d_in[24];
  const float* gwt    = (const float*)d_in[25];
  const float* c2w0   = (const float*)d_in[26];
  const float* c2b0   = (const float*)d_in[27];
  const float* c2w1   = (const float*)d_in[28];
  const float* c2w2   = (const float*)d_in[29];
  const float* pw     = (const float*)d_in[30];
  const float* pb     = (const float*)d_in[31];
  float* out = (float*)d_out;

  char* p = (char*)d_ws;
  float* ws_attn  = (float*)p; p += (size_t)E_CNT * 320 * 4;
  float* ws_apre  = (float*)p; p += (size_t)E_CNT * 8 * 4;
  float* ws_ex    = (float*)p; p += (size_t)E_CNT * 8 * 4;
  unsigned* segk  = (unsigned*)p; p += (size_t)N_NODES * 8 * 4;
  float* denom    = (float*)p; p += (size_t)N_NODES * 8 * 4;
  float* node     = (float*)p; p += (size_t)N_NODES * 1152 * 4;
  float* wT       = (float*)p; p += (size_t)3 * 128 * 64 * 4;

  hipMemsetAsync(segk, 0, N_NODES * 8 * 4, stream);
  hipMemsetAsync(denom, 0, N_NODES * 8 * 4, stream);
  hipMemsetAsync(node, 0, (size_t)N_NODES * 1152 * 4, stream);

  k_wt<<<96, 256, 0, stream>>>(pw, wT);
  k_phase1<<<E_CNT / 16, 256, 0, stream>>>(x, an, edist, eidx, wig, semb, temb,
                                           rw1, rb1, rlnw, rlnb, rw2, rb2,
                                           c1w0, c1b0, lnaw, lnab, adot,
                                           ws_attn, ws_apre);
  k_segmax<<<(E_CNT * 8) / 256, 256, 0, stream>>>(ws_apre, eidx, segk);
  k_expsum<<<(E_CNT * 8) / 256, 256, 0, stream>>>(ws_apre, eidx, segk, ws_ex, denom);
  k_phase2<<<E_CNT / 16, 256, 0, stream>>>(x, eidx, t_ij, rl_ij, winv,
                                           gwh, gwx, gwt, c2w0, c2b0, c2w1, c2w2,
                                           ws_attn, ws_ex, denom, node);
  k_proj<<<dim3((N_NODES + 31) / 32, 9), 256, 0, stream>>>(node, wT, pb, out);
}

// Round 5
// 1911.516 us; speedup vs baseline: 4.3921x; 1.3194x over previous
//
#include <hip/hip_runtime.h>

#define E_CNT 80000
#define N_NODES 10000

typedef __attribute__((ext_vector_type(8))) __bf16 bf16x8;
typedef __attribute__((ext_vector_type(4))) float f32x4;

__device__ __forceinline__ float sigmoidf_(float x) { return 1.f / (1.f + __expf(-x)); }

__device__ __forceinline__ unsigned fkey(float f) {
  unsigned u = __float_as_uint(f);
  return (u & 0x80000000u) ? ~u : (u | 0x80000000u);
}
__device__ __forceinline__ float unfkey(unsigned k) {
  unsigned u = (k & 0x80000000u) ? (k & 0x7FFFFFFFu) : ~k;
  return __uint_as_float(u);
}

// ---------------------------------------------------------------------------
// w0[:, :576] f32 -> bf16 fragment layout: w0r[(ksg*576 + col)*8 + j] where
// k = ksg*8 + j.  Lane B-frag (ks,g,col) = 16B load at ((ks*4+g)*576+col)*8.
// ---------------------------------------------------------------------------
__global__ __launch_bounds__(256) void k_w0r(const float* __restrict__ w0,
                                             __bf16* __restrict__ w0r) {
  int idx = blockIdx.x * 256 + threadIdx.x;   // 48*576 = 27648
  if (idx >= 48 * 576) return;
  int ksg = idx / 576, col = idx % 576;
#pragma unroll
  for (int j = 0; j < 8; ++j)
    w0r[(size_t)idx * 8 + j] = (__bf16)w0[(size_t)(ksg * 8 + j) * 768 + col];
}

// ---------------------------------------------------------------------------
// Phase 1. 16 edges/block, 256 threads, 3 blocks/CU (LDS ~47 KB).
// Stages 1-4 as R4; stage 5 = bf16 MFMA 16x16x32 (M=16 edges, K=384, N=576).
// ---------------------------------------------------------------------------
__global__ __launch_bounds__(256, 3) void k_phase1(
    const float* __restrict__ x, const int* __restrict__ an,
    const float* __restrict__ edist, const int* __restrict__ eidx,
    const float* __restrict__ wigner,
    const float* __restrict__ semb, const float* __restrict__ temb,
    const float* __restrict__ rw1, const float* __restrict__ rb1,
    const float* __restrict__ rlnw, const float* __restrict__ rlnb,
    const float* __restrict__ rw2, const float* __restrict__ rb2,
    const __bf16* __restrict__ w0r, const float* __restrict__ b0,
    const float* __restrict__ lnaw, const float* __restrict__ lnab,
    const float* __restrict__ adot,
    float* __restrict__ ws_attn, float* __restrict__ ws_apre)
{
  // pool: xe[16*320] (st1-2) -> rbuf[16*385] (st3-4) -> sb5[16*260] (st5-epi)
  __shared__ __align__(16) float pool[6160];
  __shared__ __align__(16) float sb[2048];
  __shared__ __align__(16) __bf16 a_lds[6144];   // [ksg=48][e=16][j=8]
  __shared__ float wgs[432];
  __shared__ int sidx[16], tidx[16], ansh[16], anth[16];

  const int tid = threadIdx.x;
  const int e0 = blockIdx.x * 16;

  if (tid < 16) {
    int s = eidx[e0 + tid], t = eidx[E_CNT + e0 + tid];
    sidx[tid] = s; tidx[tid] = t; ansh[tid] = an[s]; anth[tid] = an[t];
  }
  for (int i = tid; i < 432; i += 256) {
    int e = i / 27, r = i % 27, kk = r / 9, j = r % 9;
    int row = (kk == 0) ? 0 : (kk == 1 ? 2 : 6);
    wgs[i] = wigner[(size_t)(e0 + e) * 81 + row * 9 + j];
  }
  __syncthreads();

  // stage 1: gather x_edge -> xe (pool)
  float* xe = pool;
  for (int i = tid; i < 16 * 320; i += 256) {
    int e = i / 320, c = i % 320;
    float v;
    if (c < 64)       v = edist[(size_t)(e0 + e) * 64 + c];
    else if (c < 192) v = semb[ansh[e] * 128 + (c - 64)];
    else              v = temb[anth[e] * 128 + (c - 192)];
    xe[e * 320 + c] = v;
  }
  __syncthreads();

  // stage 2: [16,320] @ rad_w1[320,128] + b1 -> sb
  {
    int col = tid & 127, half = tid >> 7;
    float acc[8];
#pragma unroll
    for (int i = 0; i < 8; ++i) acc[i] = 0.f;
#pragma unroll 4
    for (int k = 0; k < 320; ++k) {
      float w = rw1[k * 128 + col];
#pragma unroll
      for (int i = 0; i < 8; ++i) acc[i] += xe[(half * 8 + i) * 320 + k] * w;
    }
    float bb = rb1[col];
#pragma unroll
    for (int i = 0; i < 8; ++i) sb[(half * 8 + i) * 128 + col] = acc[i] + bb;
  }
  __syncthreads();

  // stage 2b: LayerNorm(128) + scaled_silu in sb
  {
    int wid = tid >> 6, lane = tid & 63;
    for (int e = wid; e < 16; e += 4) {
      float v0 = sb[e * 128 + lane], v1 = sb[e * 128 + lane + 64];
      float s1 = v0 + v1, s2 = v0 * v0 + v1 * v1;
#pragma unroll
      for (int m = 32; m >= 1; m >>= 1) {
        s1 += __shfl_xor(s1, m);
        s2 += __shfl_xor(s2, m);
      }
      float mu = s1 * (1.f / 128.f);
      float var = s2 * (1.f / 128.f) - mu * mu;
      float rstd = rsqrtf(var + 1e-5f);
      float y0 = (v0 - mu) * rstd * rlnw[lane] + rlnb[lane];
      float y1 = (v1 - mu) * rstd * rlnw[lane + 64] + rlnb[lane + 64];
      sb[e * 128 + lane]      = y0 * sigmoidf_(y0) * (1.f / 0.6f);
      sb[e * 128 + lane + 64] = y1 * sigmoidf_(y1) * (1.f / 0.6f);
    }
  }
  __syncthreads();

  // stage 3: [16,128] @ rad_w2[:, :384] + b2 -> rbuf (pool; xe dead)
  float* rbuf = pool;
  {
    int col128 = tid & 127, half = tid >> 7;
    for (int cc = 0; cc < 3; ++cc) {
      int col = cc * 128 + col128;
      float acc[8];
#pragma unroll
      for (int i = 0; i < 8; ++i) acc[i] = 0.f;
#pragma unroll 4
      for (int k = 0; k < 128; ++k) {
        float w = rw2[k * 768 + col];
#pragma unroll
        for (int i = 0; i < 8; ++i) acc[i] += sb[(half * 8 + i) * 128 + k] * w;
      }
      float bb = rb2[col];
#pragma unroll
      for (int i = 0; i < 8; ++i) rbuf[(half * 8 + i) * 385 + col] = acc[i] + bb;
    }
  }
  __syncthreads();

  // stage 4: wigner rows {0,2,6} x cat(x_src,x_tgt), scale by r, cast bf16
  // -> a_lds fragment layout [ksg][e][j]  (ksg = kk*16 + cg, j = 0..7)
  {
    int e = tid & 15, cg = tid >> 4;
    int c0 = cg * 8;
    const float* xb = (c0 < 64) ? (x + (size_t)sidx[e] * 576 + c0)
                                : (x + (size_t)tidx[e] * 576 + (c0 - 64));
    float xc[9][8];
#pragma unroll
    for (int j = 0; j < 9; ++j) {
      float4 u0 = *(const float4*)(xb + j * 64);
      float4 u1 = *(const float4*)(xb + j * 64 + 4);
      xc[j][0] = u0.x; xc[j][1] = u0.y; xc[j][2] = u0.z; xc[j][3] = u0.w;
      xc[j][4] = u1.x; xc[j][5] = u1.y; xc[j][6] = u1.z; xc[j][7] = u1.w;
    }
#pragma unroll
    for (int kk = 0; kk < 3; ++kk) {
      float wv[9];
#pragma unroll
      for (int j = 0; j < 9; ++j) wv[j] = wgs[e * 27 + kk * 9 + j];
      __bf16* ap = a_lds + ((kk * 16 + cg) * 16 + e) * 8;
#pragma unroll
      for (int cu = 0; cu < 8; ++cu) {
        float m = 0.f;
#pragma unroll
        for (int j = 0; j < 9; ++j) m += wv[j] * xc[j][cu];
        int colc = kk * 128 + c0 + cu;
        ap[cu] = (__bf16)(m * rbuf[e * 385 + colc]);
      }
    }
  }
  __syncthreads();

  // stage 5: MFMA [16,384] @ [384,576].  Wave wv owns tiles wv*9 .. wv*9+8.
  // A: row=lane&15 (edge), k=(lane>>4)*8+j.  B: col=lane&15.  D: row=(lane>>4)*4+r.
  float* sb5 = pool;   // [e][260] (rbuf dead)
  {
    int lane = tid & 63, wv = tid >> 6;
    int erow = lane & 15, g = lane >> 4;
    bf16x8 af[12];
#pragma unroll
    for (int ks = 0; ks < 12; ++ks)
      af[ks] = *(const bf16x8*)(a_lds + ((ks * 4 + g) * 16 + erow) * 8);
    for (int tt = 0; tt < 9; ++tt) {
      int tile = wv * 9 + tt;
      int col = tile * 16 + erow;
      f32x4 acc = {0.f, 0.f, 0.f, 0.f};
#pragma unroll
      for (int ks = 0; ks < 12; ++ks) {
        bf16x8 bf = *(const bf16x8*)(w0r + ((size_t)((ks * 4 + g) * 576) + col) * 8);
        acc = __builtin_amdgcn_mfma_f32_16x16x32_bf16(af[ks], bf, acc, 0, 0, 0);
      }
      if (tile < 16) {
#pragma unroll
        for (int r = 0; r < 4; ++r) sb5[(g * 4 + r) * 260 + col] = acc[r];
      } else {
        float bb = b0[col];
#pragma unroll
        for (int r = 0; r < 4; ++r)
          ws_attn[(size_t)(e0 + g * 4 + r) * 320 + (col - 256)] = acc[r] + bb;
      }
    }
  }
  __syncthreads();

  // epilogue A: cols 0..255 -> heads (LN32 + smooth_leaky + alpha_dot)
  {
    float bb = b0[tid];
    int h = tid >> 5, kk = tid & 31;
    float lw = lnaw[kk], lb = lnab[kk], ad = adot[h * 32 + kk];
#pragma unroll
    for (int e = 0; e < 16; ++e) {
      float v = sb5[e * 260 + tid] + bb;
      float s1 = v, s2 = v * v;
#pragma unroll
      for (int m = 16; m >= 1; m >>= 1) {
        s1 += __shfl_xor(s1, m);
        s2 += __shfl_xor(s2, m);
      }
      float mu = s1 * (1.f / 32.f);
      float var = s2 * (1.f / 32.f) - mu * mu;
      float rstd = rsqrtf(var + 1e-5f);
      float xn = (v - mu) * rstd * lw + lb;
      float sl = 0.6f * xn + 0.4f * xn * (2.f * sigmoidf_(xn) - 1.f);
      float p = sl * ad;
#pragma unroll
      for (int m = 16; m >= 1; m >>= 1) p += __shfl_xor(p, m);
      if (kk == 0) ws_apre[(size_t)(e0 + e) * 8 + h] = p;
    }
  }
}

// ---------------------------------------------------------------------------
// segment max / exp-sum for softmax over tgt
// ---------------------------------------------------------------------------
__global__ __launch_bounds__(256) void k_segmax(const float* __restrict__ apre,
                                                const int* __restrict__ eidx,
                                                unsigned* __restrict__ segk) {
  int idx = blockIdx.x * 256 + threadIdx.x;
  if (idx >= E_CNT * 8) return;
  int e = idx >> 3, h = idx & 7;
  int t = eidx[E_CNT + e];
  atomicMax(&segk[t * 8 + h], fkey(apre[idx]));
}

__global__ __launch_bounds__(256) void k_expsum(const float* __restrict__ apre,
                                                const int* __restrict__ eidx,
                                                const unsigned* __restrict__ segk,
                                                float* __restrict__ ex_out,
                                                float* __restrict__ denom) {
  int idx = blockIdx.x * 256 + threadIdx.x;
  if (idx >= E_CNT * 8) return;
  int e = idx >> 3, h = idx & 7;
  int t = eidx[E_CNT + e];
  float m = unfkey(segk[t * 8 + h]);
  float ex = __expf(apre[idx] - m);
  ex_out[idx] = ex;
  atomicAdd(&denom[t * 8 + h], ex);
}

// ---------------------------------------------------------------------------
// Phase 2 (R4 verbatim): gates, message assembly, so2_conv2, alpha scale,
// wigner_inv, atomic scatter. 16 edges/block, 256 threads.
// ---------------------------------------------------------------------------
__global__ __launch_bounds__(256, 2) void k_phase2(
    const float* __restrict__ x, const int* __restrict__ eidx,
    const float* __restrict__ t_ij, const float* __restrict__ rl_ij,
    const float* __restrict__ winv,
    const float* __restrict__ gwh, const float* __restrict__ gwx, const float* __restrict__ gwt,
    const float* __restrict__ w0, const float* __restrict__ b0,
    const float* __restrict__ w1, const float* __restrict__ w2,
    const float* __restrict__ ws_attn, const float* __restrict__ ws_ex,
    const float* __restrict__ denom,
    float* __restrict__ node)
{
  __shared__ float ob[16 * 320];
  __shared__ __align__(16) float msg[16 * 576];
  __shared__ float wib[16 * 81];
  __shared__ float alp[16 * 8];
  __shared__ float rlb[16 * 8];
  __shared__ float malp[16];
  __shared__ int tnode[16];

  const int tid = threadIdx.x;
  const int e0 = blockIdx.x * 16;

  if (tid < 16) tnode[tid] = eidx[E_CNT + e0 + tid];
  __syncthreads();

  if (tid < 128) {
    int e = tid >> 3, h = tid & 7;
    float ex = ws_ex[(size_t)(e0 + e) * 8 + h];
    alp[tid] = ex / (denom[tnode[e] * 8 + h] + 1e-16f);
  } else {
    int i = tid - 128;
    int e = i >> 3;
    rlb[i] = rl_ij[(size_t)(e0 + e) * 8 + (i & 7)];
  }
  for (int i = tid; i < 16 * 81; i += 256) {
    int e = i / 81, r = i % 81;
    wib[i] = winv[(size_t)(e0 + e) * 81 + r];
  }
  for (int i = tid; i < 16 * 576; i += 256) {
    int e = i / 576, c = i % 576;
    msg[i] = x[(size_t)tnode[e] * 576 + c];
  }
  __syncthreads();
  if (tid < 16) {
    float s = 0.f;
#pragma unroll
    for (int h = 0; h < 8; ++h) s += alp[tid * 8 + h];
    malp[tid] = s * 0.125f;
  }
  __syncthreads();
  for (int i = tid; i < 16 * 320; i += 256) {
    int e = i / 320;
    ob[i] = malp[e] * ws_attn[(size_t)e0 * 320 + i];
  }
  __syncthreads();

  {
    int d = tid & 63, wid = tid >> 6;
    float acch[4] = {0.f, 0.f, 0.f, 0.f}, acct[4] = {0.f, 0.f, 0.f, 0.f};
#pragma unroll 4
    for (int k = 0; k < 64; ++k) {
      float w = gwh[k * 64 + d];
#pragma unroll
      for (int i = 0; i < 4; ++i) acch[i] += msg[(wid * 4 + i) * 576 + k] * w;
    }
#pragma unroll 4
    for (int k = 0; k < 128; ++k) {
      float w = gwt[k * 64 + d];
#pragma unroll
      for (int i = 0; i < 4; ++i) acct[i] += t_ij[(size_t)(e0 + wid * 4 + i) * 128 + k] * w;
    }
    float xp[4][8];
#pragma unroll
    for (int i = 0; i < 4; ++i)
#pragma unroll
      for (int k8 = 0; k8 < 8; ++k8) xp[i][k8] = 0.f;
#pragma unroll 2
    for (int c = 0; c < 64; ++c) {
      float w = gwx[c * 64 + d];
#pragma unroll
      for (int i = 0; i < 4; ++i) {
#pragma unroll
        for (int k8 = 0; k8 < 8; ++k8)
          xp[i][k8] += msg[(wid * 4 + i) * 576 + (k8 + 1) * 64 + c] * w;
      }
    }
    __syncthreads();
#pragma unroll
    for (int i = 0; i < 4; ++i) {
      int e = wid * 4 + i;
      float hv = acch[i]; hv = hv * sigmoidf_(hv);
      float tv = acct[i]; tv = tv * sigmoidf_(tv);
      float os  = ob[e * 320 + d];
      float od0 = ob[e * 320 + 64 + d],  od1 = ob[e * 320 + 128 + d];
      float ot0 = ob[e * 320 + 192 + d], ot1 = ob[e * 320 + 256 + d];
      msg[e * 576 + d] = os * hv;
#pragma unroll
      for (int j = 0; j < 3; ++j)
        msg[e * 576 + (1 + j) * 64 + d] = od0 * xp[i][j] + ot0 * tv * rlb[e * 8 + j];
#pragma unroll
      for (int j = 0; j < 5; ++j)
        msg[e * 576 + (4 + j) * 64 + d] = od1 * xp[i][3 + j] + ot1 * tv * rlb[e * 8 + 3 + j];
    }
  }
  __syncthreads();

  {
    int c = tid & 127, eh = tid >> 7;
    const int ebase = eh * 8;
    float m2[9][8];
    {
      float a0[3][8];
#pragma unroll
      for (int q = 0; q < 3; ++q)
#pragma unroll
        for (int ee = 0; ee < 8; ++ee) a0[q][ee] = 0.f;
#pragma unroll 2
      for (int k = 0; k < 192; ++k) {
        int row = (k < 64) ? 0 : ((k < 128) ? 2 : 6);
        int src = row * 64 + (k & 63);
        float wA = w0[k * 384 + c];
        float wB = w0[k * 384 + 128 + c];
        float wC = w0[k * 384 + 256 + c];
#pragma unroll
        for (int ee = 0; ee < 8; ++ee) {
          float a = msg[(ebase + ee) * 576 + src];
          a0[0][ee] += a * wA; a0[1][ee] += a * wB; a0[2][ee] += a * wC;
        }
      }
      float bA = b0[c], bB = b0[128 + c], bC = b0[256 + c];
#pragma unroll
      for (int ee = 0; ee < 8; ++ee) {
        m2[0][ee] = a0[0][ee] + bA;
        m2[2][ee] = a0[1][ee] + bB;
        m2[6][ee] = a0[2][ee] + bC;
      }
    }
    {
      float y0[4][8], y1[4][8];
#pragma unroll
      for (int q = 0; q < 4; ++q)
#pragma unroll
        for (int ee = 0; ee < 8; ++ee) { y0[q][ee] = 0.f; y1[q][ee] = 0.f; }
#pragma unroll 2
      for (int k = 0; k < 128; ++k) {
        int s0 = (k < 64) ? (3 * 64 + k) : (7 * 64 + k - 64);
        int s1 = (k < 64) ? (1 * 64 + k) : (5 * 64 + k - 64);
        float wA = w1[k * 512 + c],       wB = w1[k * 512 + 128 + c];
        float wC = w1[k * 512 + 256 + c], wD = w1[k * 512 + 384 + c];
#pragma unroll
        for (int ee = 0; ee < 8; ++ee) {
          float aa = msg[(ebase + ee) * 576 + s0];
          float ab = msg[(ebase + ee) * 576 + s1];
          y0[0][ee] += aa * wA; y0[1][ee] += aa * wB; y0[2][ee] += aa * wC; y0[3][ee] += aa * wD;
          y1[0][ee] += ab * wA; y1[1][ee] += ab * wB; y1[2][ee] += ab * wC; y1[3][ee] += ab * wD;
        }
      }
#pragma unroll
      for (int ee = 0; ee < 8; ++ee) {
        m2[3][ee] = y0[0][ee] - y1[2][ee];
        m2[7][ee] = y0[1][ee] - y1[3][ee];
        m2[1][ee] = y1[0][ee] + y0[2][ee];
        m2[5][ee] = y1[1][ee] + y0[3][ee];
      }
    }
    {
      float z0[2][8], z1[2][8];
#pragma unroll
      for (int q = 0; q < 2; ++q)
#pragma unroll
        for (int ee = 0; ee < 8; ++ee) { z0[q][ee] = 0.f; z1[q][ee] = 0.f; }
#pragma unroll 2
      for (int k = 0; k < 64; ++k) {
        float wA = w2[k * 256 + c], wB = w2[k * 256 + 128 + c];
#pragma unroll
        for (int ee = 0; ee < 8; ++ee) {
          float aa = msg[(ebase + ee) * 576 + 8 * 64 + k];
          float ab = msg[(ebase + ee) * 576 + 4 * 64 + k];
          z0[0][ee] += aa * wA; z0[1][ee] += aa * wB;
          z1[0][ee] += ab * wA; z1[1][ee] += ab * wB;
        }
      }
#pragma unroll
      for (int ee = 0; ee < 8; ++ee) {
        m2[8][ee] = z0[0][ee] - z1[1][ee];
        m2[4][ee] = z1[0][ee] + z0[1][ee];
      }
    }
    int h = c >> 4;
#pragma unroll
    for (int ee = 0; ee < 8; ++ee) {
      int e = ebase + ee;
      float av = alp[e * 8 + h];
      float mm[9];
#pragma unroll
      for (int j = 0; j < 9; ++j) mm[j] = m2[j][ee] * av;
      float* np = node + (size_t)tnode[e] * 1152 + c;
#pragma unroll
      for (int i = 0; i < 9; ++i) {
        float s = 0.f;
#pragma unroll
        for (int j = 0; j < 9; ++j) s += wib[e * 81 + i * 9 + j] * mm[j];
        atomicAdd(np + i * 128, s);
      }
    }
  }
}

// ---------------------------------------------------------------------------
// proj_w transpose + per-node projection (R4 verbatim)
// ---------------------------------------------------------------------------
__global__ __launch_bounds__(256) void k_wt(const float* __restrict__ pw, float* __restrict__ wT) {
  int idx = blockIdx.x * 256 + threadIdx.x;
  if (idx >= 3 * 128 * 64) return;
  int l = idx / 8192, r = idx % 8192, i = r / 64, o = r % 64;
  wT[idx] = pw[(l * 64 + o) * 128 + i];
}

__global__ __launch_bounds__(256) void k_proj(const float* __restrict__ node,
                                              const float* __restrict__ wT,
                                              const float* __restrict__ pb,
                                              float* __restrict__ out) {
  __shared__ __align__(16) float A[32 * 132];
  int k = blockIdx.y;
  int n0 = blockIdx.x * 32;
  const int lidx = (k == 0) ? 0 : (k <= 3 ? 1 : 2);
  int tid = threadIdx.x;
  for (int i = tid; i < 32 * 128; i += 256) {
    int nn = i >> 7, ii = i & 127;
    int n = n0 + nn;
    A[nn * 132 + ii] = (n < N_NODES) ? node[((size_t)n * 9 + k) * 128 + ii] : 0.f;
  }
  __syncthreads();
  int o = tid & 63, wid = tid >> 6;
  float acc[8] = {0.f, 0.f, 0.f, 0.f, 0.f, 0.f, 0.f, 0.f};
#pragma unroll 4
  for (int i = 0; i < 128; ++i) {
    float w = wT[lidx * 8192 + i * 64 + o];
#pragma unroll
    for (int r = 0; r < 8; ++r) acc[r] += A[(wid * 8 + r) * 132 + i] * w;
  }
  float bias = (k == 0) ? pb[o] : 0.f;
#pragma unroll
  for (int r = 0; r < 8; ++r) {
    int n = n0 + wid * 8 + r;
    if (n < N_NODES) out[((size_t)n * 9 + k) * 64 + o] = acc[r] + bias;
  }
}

// ---------------------------------------------------------------------------
extern "C" void kernel_launch(void* const* d_in, const int* in_sizes, int n_in,
                              void* d_out, int out_size, void* d_ws, size_t ws_size,
                              hipStream_t stream) {
  const float* x      = (const float*)d_in[0];
  const int*   an     = (const int*)d_in[1];
  const float* edist  = (const float*)d_in[2];
  const int*   eidx   = (const int*)d_in[3];
  const float* t_ij   = (const float*)d_in[4];
  const float* rl_ij  = (const float*)d_in[5];
  const float* wig    = (const float*)d_in[6];
  const float* winv   = (const float*)d_in[7];
  const float* semb   = (const float*)d_in[8];
  const float* temb   = (const float*)d_in[9];
  const float* rw1    = (const float*)d_in[10];
  const float* rb1    = (const float*)d_in[11];
  const float* rlnw   = (const float*)d_in[12];
  const float* rlnb   = (const float*)d_in[13];
  const float* rw2    = (const float*)d_in[14];
  const float* rb2    = (const float*)d_in[15];
  const float* c1w0   = (const float*)d_in[16];
  const float* c1b0   = (const float*)d_in[17];
  // d_in[18], d_in[19]: c1_wm1 / c1_wm2 — dead code in the reference
  const float* lnaw   = (const float*)d_in[20];
  const float* lnab   = (const float*)d_in[21];
  const float* adot   = (const float*)d_in[22];
  const float* gwh    = (const float*)d_in[23];
  const float* gwx    = (const float*)d_in[24];
  const float* gwt    = (const float*)d_in[25];
  const float* c2w0   = (const float*)d_in[26];
  const float* c2b0   = (const float*)d_in[27];
  const float* c2w1   = (const float*)d_in[28];
  const float* c2w2   = (const float*)d_in[29];
  const float* pw     = (const float*)d_in[30];
  const float* pb     = (const float*)d_in[31];
  float* out = (float*)d_out;

  char* p = (char*)d_ws;
  float* ws_attn  = (float*)p; p += (size_t)E_CNT * 320 * 4;
  float* ws_apre  = (float*)p; p += (size_t)E_CNT * 8 * 4;
  float* ws_ex    = (float*)p; p += (size_t)E_CNT * 8 * 4;
  unsigned* segk  = (unsigned*)p; p += (size_t)N_NODES * 8 * 4;
  float* denom    = (float*)p; p += (size_t)N_NODES * 8 * 4;
  float* node     = (float*)p; p += (size_t)N_NODES * 1152 * 4;
  float* wT       = (float*)p; p += (size_t)3 * 128 * 64 * 4;
  __bf16* w0r     = (__bf16*)p; p += (size_t)48 * 576 * 8 * 2;

  hipMemsetAsync(segk, 0, N_NODES * 8 * 4, stream);
  hipMemsetAsync(denom, 0, N_NODES * 8 * 4, stream);
  hipMemsetAsync(node, 0, (size_t)N_NODES * 1152 * 4, stream);

  k_w0r<<<108, 256, 0, stream>>>(c1w0, w0r);
  k_wt<<<96, 256, 0, stream>>>(pw, wT);
  k_phase1<<<E_CNT / 16, 256, 0, stream>>>(x, an, edist, eidx, wig, semb, temb,
                                           rw1, rb1, rlnw, rlnb, rw2, rb2,
                                           w0r, c1b0, lnaw, lnab, adot,
                                           ws_attn, ws_apre);
  k_segmax<<<(E_CNT * 8) / 256, 256, 0, stream>>>(ws_apre, eidx, segk);
  k_expsum<<<(E_CNT * 8) / 256, 256, 0, stream>>>(ws_apre, eidx, segk, ws_ex, denom);
  k_phase2<<<E_CNT / 16, 256, 0, stream>>>(x, eidx, t_ij, rl_ij, winv,
                                           gwh, gwx, gwt, c2w0, c2b0, c2w1, c2w2,
                                           ws_attn, ws_ex, denom, node);
  k_proj<<<dim3((N_NODES + 31) / 32, 9), 256, 0, stream>>>(node, wT, pb, out);
}